// Round 6
// baseline (218.750 us; speedup 1.0000x reference)
//
#include <hip/hip_runtime.h>

// Problem constants
#define BSZ 128
#define NV 321
#define IN_DIM 336
#define OUT_DIM 96
#define NC 8
#define ROWS (BSZ * NV)   // 41088
#define KSTEPS 11         // K padded to 352 (bias folded at k=336)
#define NCH (NC * KSTEPS) // 88 chunks of 32-k
#define CHUNK_HALFS 3072  // 4 kgroups x 96 cols x 8 halfs
#define DPTH 5            // register-ring prefetch depth (chunks)

typedef _Float16 half8 __attribute__((ext_vector_type(8)));
typedef float floatx4 __attribute__((ext_vector_type(4)));
typedef float floatx2 __attribute__((ext_vector_type(2)));

// ---------------------------------------------------------------------------
// Kernel 1: W (8,96,336) f32 + b (8,96) f32 -> chunked fp16 layout:
// w16p[chunk = c*11+ks][kgroup = kk/8][o][kk%8], bias folded at k==336.
// A 16-lane fragment load then covers 256 contiguous bytes (coalesced).
// ---------------------------------------------------------------------------
__global__ __launch_bounds__(256) void convert_w_kernel(
    const float* __restrict__ W, const float* __restrict__ b,
    _Float16* __restrict__ w16p) {
  int t = blockIdx.x * 256 + threadIdx.x;
  if (t >= NCH * OUT_DIM * 4) return;  // one half8 per thread
  int lg = t & 3;             // kgroup
  int o = (t >> 2) % OUT_DIM;
  int chunk = (t >> 2) / OUT_DIM;
  int ks = chunk % KSTEPS;
  int c = chunk / KSTEPS;
  int k0 = ks * 32 + lg * 8;
  const float* wr = W + (size_t)(c * OUT_DIM + o) * IN_DIM;
  half8 h;
#pragma unroll
  for (int j = 0; j < 8; ++j) {
    int k = k0 + j;
    float v = (k < IN_DIM) ? wr[k] : ((k == IN_DIM) ? b[c * OUT_DIM + o] : 0.0f);
    h[j] = (_Float16)v;
  }
  *(half8*)(w16p + (size_t)chunk * CHUNK_HALFS + lg * 768 + o * 8) = h;
}

__device__ __forceinline__ half8 cvt8(floatx4 f0, floatx4 f1) {
  half8 h;
  h[0] = (_Float16)f0[0]; h[1] = (_Float16)f0[1];
  h[2] = (_Float16)f0[2]; h[3] = (_Float16)f0[3];
  h[4] = (_Float16)f1[0]; h[5] = (_Float16)f1[1];
  h[6] = (_Float16)f1[2]; h[7] = (_Float16)f1[3];
  return h;
}

// ---------------------------------------------------------------------------
// Kernel 2: fused cluster GEMM, BARRIER-FREE main loop.
// 64 rows/block, 4 waves (2 wm x 2 wc), wave tile 32 rows x 48 cols.
// A (x, fp16, bias folded) register-resident. B streamed per-wave straight
// from L1/L2 into a 5-deep register ring (3 x half8 per chunk), fully
// unrolled 88-step loop (all indices static), issue-then-vmcnt(15).
// Duplicate B reads between wm-pair waves dedup in L1 (same CU).
// ---------------------------------------------------------------------------
__global__ __launch_bounds__(256, 2) void cluster_gemm_kernel(
    const float* __restrict__ x, const float* __restrict__ prob,
    const _Float16* __restrict__ w16p, float* __restrict__ out) {
  __shared__ float probs[64 * NC];

  const int tid = threadIdx.x;
  const int rbase = blockIdx.x * 64;
  const int lane = tid & 63;
  const int wave = tid >> 6;   // 0..3
  const int wm = wave >> 1;    // row half
  const int wc = wave & 1;     // col half
  const int l15 = lane & 15;
  const int lg = lane >> 4;    // 0..3

  // ---- prob -> LDS (64 rows x 8 clusters f32); only barrier is for this
  {
    floatx2 v = *(const floatx2*)(prob + (size_t)rbase * NC + tid * 2);
    *(floatx2*)&probs[tid * 2] = v;
  }

  // ---- A tile -> registers (fp16), bias folded at k==336
  half8 a[2][KSTEPS];
#pragma unroll
  for (int m = 0; m < 2; ++m) {
    const float* xr = x + (size_t)(rbase + wm * 32 + m * 16 + l15) * IN_DIM + lg * 8;
#pragma unroll
    for (int ks = 0; ks < 10; ++ks) {
      floatx4 f0 = *(const floatx4*)(xr + ks * 32);
      floatx4 f1 = *(const floatx4*)(xr + ks * 32 + 4);
      a[m][ks] = cvt8(f0, f1);
    }
    if (lg < 2) {  // k = 320 + lg*8 + j  (< 336)
      floatx4 f0 = *(const floatx4*)(xr + 320);
      floatx4 f1 = *(const floatx4*)(xr + 320 + 4);
      a[m][10] = cvt8(f0, f1);
    } else {
      half8 z = {};
      if (lg == 2) z[0] = (_Float16)1.0f;  // bias column
      a[m][10] = z;
    }
  }

  // drain globals (vmcnt clean for ring counting) + make probs visible
  asm volatile("s_waitcnt vmcnt(0) lgkmcnt(0)" ::: "memory");
  __syncthreads();

  // ---- per-thread B fragment base: [lg][o][8], o = wc*48 + n*16 + l15
  const _Float16* bq = w16p + lg * 768 + (wc * 48 + l15) * 8;

  // ---- register ring: DPTH chunks x 3 fragments
  half8 ring[DPTH][3];
#pragma unroll
  for (int p = 0; p < DPTH; ++p) {
    ring[p][0] = *(const half8*)(bq + p * CHUNK_HALFS);
    ring[p][1] = *(const half8*)(bq + p * CHUNK_HALFS + 128);
    ring[p][2] = *(const half8*)(bq + p * CHUNK_HALFS + 256);
  }

  floatx4 oacc[2][3] = {};
  floatx4 acc[2][3] = {};

#pragma unroll
  for (int it = 0; it < NCH; ++it) {
    const int ks = it % KSTEPS;        // static after unroll
    const int c = it / KSTEPS;         // static after unroll
    const int slot = it % DPTH;        // static after unroll

    // issue prefetch of chunk it+DPTH (clamped; extra chunk-87 loads harmless)
    const int pc = (it + DPTH < NCH) ? (it + DPTH) : (NCH - 1);
    half8 n0 = *(const half8*)(bq + pc * CHUNK_HALFS);
    half8 n1 = *(const half8*)(bq + pc * CHUNK_HALFS + 128);
    half8 n2 = *(const half8*)(bq + pc * CHUNK_HALFS + 256);

    // chunk `it` resident: 18 outstanding -> retire oldest 3
    asm volatile("s_waitcnt vmcnt(15)" ::: "memory");

    acc[0][0] = __builtin_amdgcn_mfma_f32_16x16x32_f16(a[0][ks], ring[slot][0], acc[0][0], 0, 0, 0);
    acc[1][0] = __builtin_amdgcn_mfma_f32_16x16x32_f16(a[1][ks], ring[slot][0], acc[1][0], 0, 0, 0);
    acc[0][1] = __builtin_amdgcn_mfma_f32_16x16x32_f16(a[0][ks], ring[slot][1], acc[0][1], 0, 0, 0);
    acc[1][1] = __builtin_amdgcn_mfma_f32_16x16x32_f16(a[1][ks], ring[slot][1], acc[1][1], 0, 0, 0);
    acc[0][2] = __builtin_amdgcn_mfma_f32_16x16x32_f16(a[0][ks], ring[slot][2], acc[0][2], 0, 0, 0);
    acc[1][2] = __builtin_amdgcn_mfma_f32_16x16x32_f16(a[1][ks], ring[slot][2], acc[1][2], 0, 0, 0);

    if (ks == KSTEPS - 1) {  // cluster boundary: prob-weighted accumulate (LDS)
#pragma unroll
      for (int m = 0; m < 2; ++m) {
#pragma unroll
        for (int r = 0; r < 4; ++r) {
          float p = probs[(wm * 32 + m * 16 + lg * 4 + r) * NC + c];
          oacc[m][0][r] += p * acc[m][0][r];
          oacc[m][1][r] += p * acc[m][1][r];
          oacc[m][2][r] += p * acc[m][2][r];
        }
        acc[m][0] = (floatx4){0.f, 0.f, 0.f, 0.f};
        acc[m][1] = (floatx4){0.f, 0.f, 0.f, 0.f};
        acc[m][2] = (floatx4){0.f, 0.f, 0.f, 0.f};
      }
    }

    // rotate ring (SSA rename; consumed-before-overwritten)
    ring[slot][0] = n0; ring[slot][1] = n1; ring[slot][2] = n2;
  }

  // ---- store: D layout col = l15, row = lg*4 + r
#pragma unroll
  for (int m = 0; m < 2; ++m) {
#pragma unroll
    for (int n = 0; n < 3; ++n) {
#pragma unroll
      for (int r = 0; r < 4; ++r) {
        int grow = rbase + wm * 32 + m * 16 + lg * 4 + r;
        out[(size_t)grow * OUT_DIM + wc * 48 + n * 16 + l15] = oacc[m][n][r];
      }
    }
  }
}

// ---------------------------------------------------------------------------
extern "C" void kernel_launch(void* const* d_in, const int* in_sizes, int n_in,
                              void* d_out, int out_size, void* d_ws, size_t ws_size,
                              hipStream_t stream) {
  const float* x = (const float*)d_in[0];     // (128,321,336)
  const float* prob = (const float*)d_in[1];  // (128,321,8)
  const float* W = (const float*)d_in[2];     // (8,96,336)
  const float* b = (const float*)d_in[3];     // (8,96)
  float* out = (float*)d_out;                 // (128,321,96)
  _Float16* w16p = (_Float16*)d_ws;           // 88 chunks * 6144 B = 540,672 B

  const int ct = NCH * OUT_DIM * 4;           // one half8 per thread
  hipLaunchKernelGGL(convert_w_kernel, dim3((ct + 255) / 256), dim3(256), 0,
                     stream, W, b, w16p);
  hipLaunchKernelGGL(cluster_gemm_kernel, dim3(ROWS / 64), dim3(256), 0, stream,
                     x, prob, w16p, out);
}

// Round 7
// 188.707 us; speedup vs baseline: 1.1592x; 1.1592x over previous
//
#include <hip/hip_runtime.h>

// Problem constants
#define BSZ 128
#define NV 321
#define IN_DIM 336
#define OUT_DIM 96
#define NC 8
#define ROWS (BSZ * NV)   // 41088
#define KSTEPS 11         // K padded to 352 (bias folded at k=336)
#define NCH (NC * KSTEPS) // 88 chunks of 32-k
#define CHUNK_HALFS 3072  // 4 kgroups x 96 cols x 8 halfs
#define LDK 360           // xs row stride in halfs (conflict-benign, v1-measured)

typedef _Float16 half8 __attribute__((ext_vector_type(8)));
typedef _Float16 half4 __attribute__((ext_vector_type(4)));
typedef float floatx4 __attribute__((ext_vector_type(4)));
typedef float floatx2 __attribute__((ext_vector_type(2)));

// ---------------------------------------------------------------------------
// Kernel 1: W (8,96,336) f32 + b (8,96) f32 -> chunked fp16 layout:
// w16p[chunk = c*11+ks][kgroup = kk/8][o][kk%8], bias folded at k==336.
// A 16-lane B-fragment load covers 256 contiguous bytes (coalesced).
// ---------------------------------------------------------------------------
__global__ __launch_bounds__(256) void convert_w_kernel(
    const float* __restrict__ W, const float* __restrict__ b,
    _Float16* __restrict__ w16p) {
  int t = blockIdx.x * 256 + threadIdx.x;
  if (t >= NCH * OUT_DIM * 4) return;  // one half8 per thread
  int lg = t & 3;             // kgroup
  int o = (t >> 2) % OUT_DIM;
  int chunk = (t >> 2) / OUT_DIM;
  int ks = chunk % KSTEPS;
  int c = chunk / KSTEPS;
  int k0 = ks * 32 + lg * 8;
  const float* wr = W + (size_t)(c * OUT_DIM + o) * IN_DIM;
  half8 h;
#pragma unroll
  for (int j = 0; j < 8; ++j) {
    int k = k0 + j;
    float v = (k < IN_DIM) ? wr[k] : ((k == IN_DIM) ? b[c * OUT_DIM + o] : 0.0f);
    h[j] = (_Float16)v;
  }
  *(half8*)(w16p + (size_t)chunk * CHUNK_HALFS + lg * 768 + o * 8) = h;
}

// ---------------------------------------------------------------------------
// Kernel 2: fused cluster GEMM, barrier-free main loop.
// 64 rows/block, 4 waves (2 wm x 2 wc), wave tile 32 rows x 48 cols.
// A (x fp16, bias folded) in LDS, staged once (one __syncthreads total).
// B streams L2 -> registers: ring[11][3] indexed by STATIC ks (inner loop
// unrolled by 11 only); prefetch distance 10 targets ring[(ks+10)%11] =
// the slot consumed last iteration (WAR-free, no copies, no runtime index).
// Compiler emits the vmcnt for the 10-iteration-old load dependency.
// ---------------------------------------------------------------------------
__global__ __launch_bounds__(256, 2) void cluster_gemm_kernel(
    const float* __restrict__ x, const float* __restrict__ prob,
    const _Float16* __restrict__ w16p, float* __restrict__ out) {
  __shared__ __align__(16) _Float16 xs[64 * LDK];
  __shared__ float probs[64 * NC];

  const int tid = threadIdx.x;
  const int rbase = blockIdx.x * 64;
  const int lane = tid & 63;
  const int wave = tid >> 6;   // 0..3
  const int wm = wave >> 1;    // row half
  const int wc = wave & 1;     // col half
  const int l15 = lane & 15;
  const int lg = lane >> 4;    // 0..3

  // ---- prob -> LDS (64 rows x 8 clusters f32)
  {
    floatx2 v = *(const floatx2*)(prob + (size_t)rbase * NC + tid * 2);
    *(floatx2*)&probs[tid * 2] = v;
  }

  // ---- x tile -> LDS fp16: 64 rows x 336, bias=1.0 at k=336, zeros to 360
  {
    int row = tid >> 2;   // 0..63
    int q = tid & 3;      // quarter-row: 84 floats
    const float* src = x + (size_t)(rbase + row) * IN_DIM + q * 84;
    _Float16* dst = xs + row * LDK + q * 84;
#pragma unroll
    for (int j = 0; j < 21; ++j) {
      floatx4 v = *(const floatx4*)(src + j * 4);
      half4 h = {(_Float16)v[0], (_Float16)v[1], (_Float16)v[2], (_Float16)v[3]};
      *(half4*)(dst + j * 4) = h;
    }
    if (tid < 64) {
      _Float16* p = xs + tid * LDK + IN_DIM;
      p[0] = (_Float16)1.0f;     // bias column
#pragma unroll
      for (int k = 1; k < LDK - IN_DIM; ++k) p[k] = (_Float16)0.0f;
    }
  }
  __syncthreads();  // the only block-wide sync

  // ---- B ring prologue: chunks 0..9 -> ring[0..9] (ring[10] fills at it=0)
  const _Float16* bq = w16p + lg * 768 + (wc * 48 + l15) * 8;
  half8 ring[KSTEPS][3];
#pragma unroll
  for (int p = 0; p < 10; ++p) {
    ring[p][0] = *(const half8*)(bq + p * CHUNK_HALFS);
    ring[p][1] = *(const half8*)(bq + p * CHUNK_HALFS + 128);
    ring[p][2] = *(const half8*)(bq + p * CHUNK_HALFS + 256);
  }

  // ---- A fragment base: row = wm*32 + m*16 + l15, k = lg*8 + ks*32
  const _Float16* a_base = xs + (wm * 32 + l15) * LDK + lg * 8;

  // preload A(ks=0)
  half8 acur0 = *(const half8*)(a_base);
  half8 acur1 = *(const half8*)(a_base + 16 * LDK);

  floatx4 oacc[2][3] = {};
  floatx4 acc[2][3] = {};

  for (int c = 0; c < NC; ++c) {
    const int itbase = c * KSTEPS;
#pragma unroll
    for (int ks = 0; ks < KSTEPS; ++ks) {
      // prefetch chunk it+10 (clamped; tail re-loads chunk 87 into dead slots)
      int chunkp = itbase + ks + 10;
      if (chunkp > NCH - 1) chunkp = NCH - 1;
      const int kdst = (ks + 10) % KSTEPS;  // static: slot consumed last iter
      const _Float16* pf = bq + (size_t)chunkp * CHUNK_HALFS;
      ring[kdst][0] = *(const half8*)(pf);
      ring[kdst][1] = *(const half8*)(pf + 128);
      ring[kdst][2] = *(const half8*)(pf + 256);

      // pipelined A read for next kstep
      const int ks2 = (ks + 1) % KSTEPS;
      half8 an0 = *(const half8*)(a_base + ks2 * 32);
      half8 an1 = *(const half8*)(a_base + 16 * LDK + ks2 * 32);

      // MFMA on current kstep (B loaded 10 iterations ago)
      acc[0][0] = __builtin_amdgcn_mfma_f32_16x16x32_f16(acur0, ring[ks][0], acc[0][0], 0, 0, 0);
      acc[1][0] = __builtin_amdgcn_mfma_f32_16x16x32_f16(acur1, ring[ks][0], acc[1][0], 0, 0, 0);
      acc[0][1] = __builtin_amdgcn_mfma_f32_16x16x32_f16(acur0, ring[ks][1], acc[0][1], 0, 0, 0);
      acc[1][1] = __builtin_amdgcn_mfma_f32_16x16x32_f16(acur1, ring[ks][1], acc[1][1], 0, 0, 0);
      acc[0][2] = __builtin_amdgcn_mfma_f32_16x16x32_f16(acur0, ring[ks][2], acc[0][2], 0, 0, 0);
      acc[1][2] = __builtin_amdgcn_mfma_f32_16x16x32_f16(acur1, ring[ks][2], acc[1][2], 0, 0, 0);

      if (ks == KSTEPS - 1) {  // cluster boundary: prob-weighted accumulate
#pragma unroll
        for (int m = 0; m < 2; ++m) {
#pragma unroll
          for (int r = 0; r < 4; ++r) {
            float p = probs[(wm * 32 + m * 16 + lg * 4 + r) * NC + c];
            oacc[m][0][r] += p * acc[m][0][r];
            oacc[m][1][r] += p * acc[m][1][r];
            oacc[m][2][r] += p * acc[m][2][r];
          }
          acc[m][0] = (floatx4){0.f, 0.f, 0.f, 0.f};
          acc[m][1] = (floatx4){0.f, 0.f, 0.f, 0.f};
          acc[m][2] = (floatx4){0.f, 0.f, 0.f, 0.f};
        }
      }

      acur0 = an0; acur1 = an1;
    }
  }

  // ---- store: D layout col = l15, row = lg*4 + r
#pragma unroll
  for (int m = 0; m < 2; ++m) {
#pragma unroll
    for (int n = 0; n < 3; ++n) {
#pragma unroll
      for (int r = 0; r < 4; ++r) {
        int grow = rbase + wm * 32 + m * 16 + lg * 4 + r;
        out[(size_t)grow * OUT_DIM + wc * 48 + n * 16 + l15] = oacc[m][n][r];
      }
    }
  }
}

// ---------------------------------------------------------------------------
extern "C" void kernel_launch(void* const* d_in, const int* in_sizes, int n_in,
                              void* d_out, int out_size, void* d_ws, size_t ws_size,
                              hipStream_t stream) {
  const float* x = (const float*)d_in[0];     // (128,321,336)
  const float* prob = (const float*)d_in[1];  // (128,321,8)
  const float* W = (const float*)d_in[2];     // (8,96,336)
  const float* b = (const float*)d_in[3];     // (8,96)
  float* out = (float*)d_out;                 // (128,321,96)
  _Float16* w16p = (_Float16*)d_ws;           // 88 chunks * 6144 B = 540,672 B

  const int ct = NCH * OUT_DIM * 4;           // one half8 per thread
  hipLaunchKernelGGL(convert_w_kernel, dim3((ct + 255) / 256), dim3(256), 0,
                     stream, W, b, w16p);
  hipLaunchKernelGGL(cluster_gemm_kernel, dim3(ROWS / 64), dim3(256), 0, stream,
                     x, prob, w16p, out);
}